// Round 2
// baseline (2079.249 us; speedup 1.0000x reference)
//
#include <hip/hip_runtime.h>
#include <hip/hip_fp16.h>
#include <hip/hip_cooperative_groups.h>
#include <math.h>

namespace cg = cooperative_groups;

#define BB 8
#define NN 1024
#define DD 64
#define EPSF 0.05f
#define MAX_ITER 100
// threshold on SUM of |du| over B*N (reference: mean < 1e-6)
#define ERR_SUM_THRESH 8.192e-3f
// 1/(eps*ln2) and eps*ln2
#define SCALE_ 28.853900817779268f
#define EPSLN2_ 0.034657359027997264f

#if __has_builtin(__builtin_amdgcn_exp2f)
static __device__ __forceinline__ float fexp2(float x) { return __builtin_amdgcn_exp2f(x); }
#else
static __device__ __forceinline__ float fexp2(float x) { return __expf(x * 0.69314718056f); }
#endif
#if __has_builtin(__builtin_amdgcn_logf)
static __device__ __forceinline__ float flog2(float x) { return __builtin_amdgcn_logf(x); }
#else
static __device__ __forceinline__ float flog2(float x) { return __logf(x) * 1.4426950408890f; }
#endif

__device__ __forceinline__ float wave_sum64(float x) {
#pragma unroll
    for (int off = 1; off < 64; off <<= 1) x += __shfl_xor(x, off);
    return x;
}
__device__ __forceinline__ float readlane_f(float x, int l) {
    return __uint_as_float(__builtin_amdgcn_readlane(__float_as_uint(x), l));
}

// ---------------- normalize rows of (nrows, 64) ----------------
__global__ __launch_bounds__(256) void norm_kernel(const float* __restrict__ in,
                                                   float* __restrict__ out, int nrows) {
    int wave = (blockIdx.x * blockDim.x + threadIdx.x) >> 6;
    int lane = threadIdx.x & 63;
    if (wave >= nrows) return;
    float x = in[(size_t)wave * DD + lane];
    float ss = wave_sum64(x * x);
    float n = fmaxf(sqrtf(ss), 1e-12f);
    out[(size_t)wave * DD + lane] = x / n;
}

// ---------------- C = 1 - Qn Kn^T, store fp16 C and C^T ----------------
__global__ __launch_bounds__(256) void cost_kernel(const float* __restrict__ Q,
                                                   const float* __restrict__ K,
                                                   _Float16* __restrict__ C,
                                                   _Float16* __restrict__ CT) {
    __shared__ float Qs[64][65];
    __shared__ float Ks[64][65];
    int b = blockIdx.z;
    int i0 = blockIdx.y * 64, j0 = blockIdx.x * 64;
    const float* Qb = Q + ((size_t)b * NN + i0) * DD;
    const float* Kb = K + ((size_t)b * NN + j0) * DD;
    int tx = threadIdx.x, ty = threadIdx.y;
    int tid = ty * 16 + tx;
#pragma unroll
    for (int kk = 0; kk < 4; ++kk) {
        int c = tid + 256 * kk;
        int row = c >> 4;
        int c4 = c & 15;
        float4 qv = ((const float4*)(Qb + row * DD))[c4];
        Qs[row][c4 * 4 + 0] = qv.x; Qs[row][c4 * 4 + 1] = qv.y;
        Qs[row][c4 * 4 + 2] = qv.z; Qs[row][c4 * 4 + 3] = qv.w;
        float4 kv = ((const float4*)(Kb + row * DD))[c4];
        Ks[row][c4 * 4 + 0] = kv.x; Ks[row][c4 * 4 + 1] = kv.y;
        Ks[row][c4 * 4 + 2] = kv.z; Ks[row][c4 * 4 + 3] = kv.w;
    }
    __syncthreads();
    float acc[4][4] = {};
#pragma unroll 16
    for (int d = 0; d < 64; ++d) {
        float qv[4], kv[4];
#pragma unroll
        for (int rr = 0; rr < 4; ++rr) qv[rr] = Qs[ty * 4 + rr][d];
#pragma unroll
        for (int cc = 0; cc < 4; ++cc) kv[cc] = Ks[tx * 4 + cc][d];
#pragma unroll
        for (int rr = 0; rr < 4; ++rr)
#pragma unroll
            for (int cc = 0; cc < 4; ++cc) acc[rr][cc] += qv[rr] * kv[cc];
    }
#pragma unroll
    for (int rr = 0; rr < 4; ++rr)
#pragma unroll
        for (int cc = 0; cc < 4; ++cc) {
            int gi = i0 + ty * 4 + rr, gj = j0 + tx * 4 + cc;
            float cv = 1.0f - acc[rr][cc];
            C[((size_t)b * NN + gi) * NN + gj] = (_Float16)cv;
            CT[((size_t)b * NN + gj) * NN + gi] = (_Float16)cv;
        }
}

// ---------------- cooperative Sinkhorn loop ----------------
// 1024 blocks x 256 threads; block bk owns rows bk*8 .. bk*8+7 of both C and CT.
// Each wave owns 2 C-rows + 2 CT-rows, pre-converted to fp32 and pre-scaled by
// -SCALE_, register-resident across all iterations (lane holds j = k*64+lane).
__global__ __launch_bounds__(256, 4) void coop_sink(const _Float16* __restrict__ C,
                                                    const _Float16* __restrict__ CT,
                                                    float* __restrict__ u,
                                                    float* __restrict__ v,
                                                    float* __restrict__ err,
                                                    float eln) {
    cg::grid_group grid = cg::this_grid();
    __shared__ float sv[NN];
    __shared__ float sdelta[4];
    int tid = threadIdx.x;
    int w = tid >> 6, lane = tid & 63;
    int bk = blockIdx.x;
    int b = bk >> 7;                 // 128 blocks per batch
    int r0 = bk * 8 + w * 2;         // this wave's first row

    float cu[2][16], cv[2][16];
#pragma unroll
    for (int rr = 0; rr < 2; ++rr) {
        const _Float16* cr = C + (size_t)(r0 + rr) * NN;
        const _Float16* tr = CT + (size_t)(r0 + rr) * NN;
#pragma unroll
        for (int k = 0; k < 16; ++k) {
            cu[rr][k] = -SCALE_ * (float)cr[k * 64 + lane];
            cv[rr][k] = -SCALE_ * (float)tr[k * 64 + lane];
        }
    }

    for (int t = 0; t < MAX_ITER; ++t) {
        // ---- u phase: u_i = eln - eps*ln sum_j exp((v_j - C_ij)/eps) ----
        {
            float4 x = ((const float4*)(v + (size_t)b * NN))[tid];
            ((float4*)sv)[tid] = make_float4(x.x * SCALE_, x.y * SCALE_, x.z * SCALE_, x.w * SCALE_);
            __syncthreads();
            float del = 0.f;
#pragma unroll
            for (int rr = 0; rr < 2; ++rr) {
                float s0 = 0.f, s1 = 0.f, s2 = 0.f, s3 = 0.f;
#pragma unroll
                for (int k = 0; k < 16; k += 4) {
                    s0 += fexp2(cu[rr][k + 0] + sv[(k + 0) * 64 + lane]);
                    s1 += fexp2(cu[rr][k + 1] + sv[(k + 1) * 64 + lane]);
                    s2 += fexp2(cu[rr][k + 2] + sv[(k + 2) * 64 + lane]);
                    s3 += fexp2(cu[rr][k + 3] + sv[(k + 3) * 64 + lane]);
                }
                float s = wave_sum64((s0 + s1) + (s2 + s3));
                float unew = eln - EPSLN2_ * flog2(s);
                if (lane == 0) {
                    int r = r0 + rr;
                    del += fabsf(unew - u[r]);
                    u[r] = unew;
                }
            }
            if (lane == 0) sdelta[w] = del;
            __syncthreads();
            if (tid == 0) atomicAdd(err + t, sdelta[0] + sdelta[1] + sdelta[2] + sdelta[3]);
        }
        grid.sync();
        // ---- v phase: v_j = eln - eps*ln sum_i exp((u_i - C_ij)/eps) ----
        {
            float4 x = ((const float4*)(u + (size_t)b * NN))[tid];
            ((float4*)sv)[tid] = make_float4(x.x * SCALE_, x.y * SCALE_, x.z * SCALE_, x.w * SCALE_);
            __syncthreads();
#pragma unroll
            for (int rr = 0; rr < 2; ++rr) {
                float s0 = 0.f, s1 = 0.f, s2 = 0.f, s3 = 0.f;
#pragma unroll
                for (int k = 0; k < 16; k += 4) {
                    s0 += fexp2(cv[rr][k + 0] + sv[(k + 0) * 64 + lane]);
                    s1 += fexp2(cv[rr][k + 1] + sv[(k + 1) * 64 + lane]);
                    s2 += fexp2(cv[rr][k + 2] + sv[(k + 2) * 64 + lane]);
                    s3 += fexp2(cv[rr][k + 3] + sv[(k + 3) * 64 + lane]);
                }
                float s = wave_sum64((s0 + s1) + (s2 + s3));
                float vnew = eln - EPSLN2_ * flog2(s);
                if (lane == 0) v[r0 + rr] = vnew;
            }
            __syncthreads();
        }
        grid.sync();
        float e = __hip_atomic_load(err + t, __ATOMIC_RELAXED, __HIP_MEMORY_SCOPE_AGENT);
        if (e < ERR_SUM_THRESH) break;   // uniform across grid
    }
}

// ---------------- out = T@V + V, T = exp((u_i + v_j - C_ij)/eps) ----------------
// 512 blocks x 256 threads; block handles 16 rows (4 per wave), LDS-staged V tile.
__global__ __launch_bounds__(256) void final_kernel(const _Float16* __restrict__ C,
                                                    const float* __restrict__ u,
                                                    const float* __restrict__ v,
                                                    const float* __restrict__ V,
                                                    float* __restrict__ out) {
    __shared__ float Vs[64 * 64];
    int tid = threadIdx.x;
    int w = tid >> 6, lane = tid & 63;
    int R0 = blockIdx.x * 16;        // global row base
    int b = R0 >> 10;
    const float* Vb = V + (size_t)b * NN * DD;
    const float* vb = v + (size_t)b * NN;
    float su[4];
#pragma unroll
    for (int rr = 0; rr < 4; ++rr) su[rr] = u[R0 + w * 4 + rr] * SCALE_;
    float acc[4] = {0.f, 0.f, 0.f, 0.f};

    for (int j0 = 0; j0 < NN; j0 += 64) {
        __syncthreads();
        const float4* src = (const float4*)(Vb + (size_t)j0 * DD);
        float4* dst = (float4*)Vs;
#pragma unroll
        for (int k2 = 0; k2 < 4; ++k2) dst[tid + 256 * k2] = src[tid + 256 * k2];
        __syncthreads();
        float vsc = vb[j0 + lane] * SCALE_;
        float wt[4];
#pragma unroll
        for (int rr = 0; rr < 4; ++rr) {
            float c = (float)C[(size_t)(R0 + w * 4 + rr) * NN + j0 + lane];
            wt[rr] = fexp2(fmaf(c, -SCALE_, su[rr] + vsc));
        }
#pragma unroll 64
        for (int jj = 0; jj < 64; ++jj) {
            float vv = Vs[jj * 64 + lane];
            acc[0] += readlane_f(wt[0], jj) * vv;
            acc[1] += readlane_f(wt[1], jj) * vv;
            acc[2] += readlane_f(wt[2], jj) * vv;
            acc[3] += readlane_f(wt[3], jj) * vv;
        }
    }
    int i0 = R0 & (NN - 1);
#pragma unroll
    for (int rr = 0; rr < 4; ++rr)
        out[(size_t)(R0 + w * 4 + rr) * DD + lane] =
            acc[rr] + Vb[(size_t)(i0 + w * 4 + rr) * DD + lane];
}

extern "C" void kernel_launch(void* const* d_in, const int* in_sizes, int n_in,
                              void* d_out, int out_size, void* d_ws, size_t ws_size,
                              hipStream_t stream) {
    const float* q = (const float*)d_in[0];
    const float* k = (const float*)d_in[1];
    const float* V = (const float*)d_in[2];
    float* out = (float*)d_out;

    char* ws = (char*)d_ws;
    const size_t C_BYTES = (size_t)BB * NN * NN * sizeof(_Float16);   // 16 MB
    _Float16* C  = (_Float16*)ws;
    _Float16* CT = (_Float16*)(ws + C_BYTES);
    float* Qn = (float*)(ws + 2 * C_BYTES);
    float* Kn = (float*)(ws + 2 * C_BYTES + (size_t)BB * NN * DD * 4);
    float* u  = (float*)(ws + 2 * C_BYTES + 2 * (size_t)BB * NN * DD * 4);
    float* v  = u + BB * NN;
    float* err = v + BB * NN;

    hipMemsetAsync(u, 0, (2 * BB * NN + MAX_ITER + 28) * sizeof(float), stream);

    norm_kernel<<<2048, 256, 0, stream>>>(q, Qn, BB * NN);
    norm_kernel<<<2048, 256, 0, stream>>>(k, Kn, BB * NN);
    cost_kernel<<<dim3(16, 16, 8), dim3(16, 16), 0, stream>>>(Qn, Kn, C, CT);

    float eln = EPSF * logf(1.0f / NN + 1e-8f);
    void* args[6];
    args[0] = &C; args[1] = &CT; args[2] = &u; args[3] = &v; args[4] = &err; args[5] = &eln;
    hipLaunchCooperativeKernel((const void*)coop_sink, dim3(1024), dim3(256),
                               args, 0, stream);

    final_kernel<<<512, 256, 0, stream>>>(C, u, v, V, out);
}

// Round 3
// 350.593 us; speedup vs baseline: 5.9307x; 5.9307x over previous
//
#include <hip/hip_runtime.h>
#include <math.h>

#define BB 8
#define NN 1024
#define DD 64
#define EPSF 0.05f
#define MAX_ITER 100
// threshold on SUM of |du| over B*N (reference: mean < 1e-6)
#define ERR_SUM_THRESH 8.192e-3f
// 1/(eps*ln2) and eps*ln2
#define SCALE_ 28.853900817779268f
#define EPSLN2_ 0.034657359027997264f
#define NBLK 256

static __device__ __forceinline__ float fexp2(float x) { return __builtin_amdgcn_exp2f(x); }
static __device__ __forceinline__ float flog2(float x) { return __builtin_amdgcn_logf(x); }
static __device__ __forceinline__ float bflo(unsigned u) { return __uint_as_float(u << 16); }
static __device__ __forceinline__ float bfhi(unsigned u) { return __uint_as_float(u & 0xffff0000u); }
static __device__ __forceinline__ float bfu(unsigned short s) { return __uint_as_float(((unsigned)s) << 16); }
static __device__ __forceinline__ unsigned short bf16rne(float x) {
    unsigned u = __float_as_uint(x);
    u += 0x7fffu + ((u >> 16) & 1u);
    return (unsigned short)(u >> 16);
}
__device__ __forceinline__ float wave_sum64(float x) {
#pragma unroll
    for (int off = 1; off < 64; off <<= 1) x += __shfl_xor(x, off);
    return x;
}

// ---------------- fused normalize + cost + exp: M = exp2(-(1-QnKn^T)*SCALE_) bf16, and MT ----------------
__global__ __launch_bounds__(256) void cost_kernel(const float* __restrict__ q,
                                                   const float* __restrict__ k,
                                                   unsigned short* __restrict__ M,
                                                   unsigned short* __restrict__ MT) {
    __shared__ float Qs[64][65];
    __shared__ float Ks[64][65];
    __shared__ float qin[64];
    __shared__ float kin[64];
    int b = blockIdx.z;
    int i0 = blockIdx.y * 64, j0 = blockIdx.x * 64;
    const float* Qb = q + ((size_t)b * NN + i0) * DD;
    const float* Kb = k + ((size_t)b * NN + j0) * DD;
    int tx = threadIdx.x, ty = threadIdx.y;
    int tid = ty * 16 + tx;
#pragma unroll
    for (int kk = 0; kk < 4; ++kk) {
        int c = tid + 256 * kk;
        int row = c >> 4;
        int c4 = c & 15;
        float4 qv = ((const float4*)(Qb + row * DD))[c4];
        Qs[row][c4 * 4 + 0] = qv.x; Qs[row][c4 * 4 + 1] = qv.y;
        Qs[row][c4 * 4 + 2] = qv.z; Qs[row][c4 * 4 + 3] = qv.w;
        float4 kv = ((const float4*)(Kb + row * DD))[c4];
        Ks[row][c4 * 4 + 0] = kv.x; Ks[row][c4 * 4 + 1] = kv.y;
        Ks[row][c4 * 4 + 2] = kv.z; Ks[row][c4 * 4 + 3] = kv.w;
    }
    __syncthreads();
    if (tid < 64) {
        float ss = 0.f;
#pragma unroll 16
        for (int d = 0; d < 64; ++d) ss += Qs[tid][d] * Qs[tid][d];
        qin[tid] = 1.0f / fmaxf(sqrtf(ss), 1e-12f);
    } else if (tid < 128) {
        int r = tid - 64;
        float ss = 0.f;
#pragma unroll 16
        for (int d = 0; d < 64; ++d) ss += Ks[r][d] * Ks[r][d];
        kin[r] = 1.0f / fmaxf(sqrtf(ss), 1e-12f);
    }
    __syncthreads();
    float acc[4][4] = {};
#pragma unroll 16
    for (int d = 0; d < 64; ++d) {
        float qv[4], kv[4];
#pragma unroll
        for (int rr = 0; rr < 4; ++rr) qv[rr] = Qs[ty * 4 + rr][d];
#pragma unroll
        for (int cc = 0; cc < 4; ++cc) kv[cc] = Ks[tx * 4 + cc][d];
#pragma unroll
        for (int rr = 0; rr < 4; ++rr)
#pragma unroll
            for (int cc = 0; cc < 4; ++cc) acc[rr][cc] += qv[rr] * kv[cc];
    }
#pragma unroll
    for (int rr = 0; rr < 4; ++rr)
#pragma unroll
        for (int cc = 0; cc < 4; ++cc) {
            int li = ty * 4 + rr, lj = tx * 4 + cc;
            int gi = i0 + li, gj = j0 + lj;
            float cv = 1.0f - acc[rr][cc] * qin[li] * kin[lj];
            unsigned short us = bf16rne(fexp2(-cv * SCALE_));
            M [((size_t)b << 20) + ((size_t)gi << 10) + gj] = us;
            MT[((size_t)b << 20) + ((size_t)gj << 10) + gi] = us;
        }
}

// ---------------- persistent Sinkhorn with hand-rolled device barrier ----------------
// 256 blocks x 256 threads (1/CU). batch = blk&7 (XCD-affine: M_b+MT_b = 4MB -> one XCD L2).
// Block owns 32 M-rows + 32 MT-rows; wave owns 8 each. u/v exchanged via agent-scope
// relaxed atomics (cache-bypass) so no L2 flushes are needed -> M stays L2-hot.
#define ACC8(U4, base)                                              \
    s0 = fmaf(bflo(U4.x), wrg[base + 0], s0);                       \
    s1 = fmaf(bfhi(U4.x), wrg[base + 1], s1);                       \
    s0 = fmaf(bflo(U4.y), wrg[base + 2], s0);                       \
    s1 = fmaf(bfhi(U4.y), wrg[base + 3], s1);                       \
    s0 = fmaf(bflo(U4.z), wrg[base + 4], s0);                       \
    s1 = fmaf(bfhi(U4.z), wrg[base + 5], s1);                       \
    s0 = fmaf(bflo(U4.w), wrg[base + 6], s0);                       \
    s1 = fmaf(bfhi(U4.w), wrg[base + 7], s1);

__global__ __launch_bounds__(256, 1) void sink_coop(const unsigned short* __restrict__ M,
                                                    const unsigned short* __restrict__ MT,
                                                    float* __restrict__ u,
                                                    float* __restrict__ v,
                                                    float* __restrict__ err,
                                                    unsigned* __restrict__ cnt,
                                                    float eln) {
    __shared__ __align__(16) float sw[NN];
    __shared__ float sdel[4];
    __shared__ int sflag;
    int tid = threadIdx.x;
    int w = tid >> 6, lane = tid & 63;
    int b = blockIdx.x & 7;
    int slice = blockIdx.x >> 3;          // 0..31
    int rbase = slice * 32 + w * 8;       // wave's first local row
    const unsigned short* Mb  = M  + ((size_t)b << 20);
    const unsigned short* MTb = MT + ((size_t)b << 20);
    float* ub = u + (b << 10);
    float* vb = v + (b << 10);
    float uprev[8];
#pragma unroll
    for (int r = 0; r < 8; ++r) uprev[r] = 0.f;

    for (int t = 0; t < MAX_ITER; ++t) {
        // ---------- u phase: u_i = eln - eps*ln2*log2( sum_j M_ij * exp2(v_j*SCALE) ) ----------
        {
            float x0 = __hip_atomic_load(vb + tid * 4 + 0, __ATOMIC_RELAXED, __HIP_MEMORY_SCOPE_AGENT);
            float x1 = __hip_atomic_load(vb + tid * 4 + 1, __ATOMIC_RELAXED, __HIP_MEMORY_SCOPE_AGENT);
            float x2 = __hip_atomic_load(vb + tid * 4 + 2, __ATOMIC_RELAXED, __HIP_MEMORY_SCOPE_AGENT);
            float x3 = __hip_atomic_load(vb + tid * 4 + 3, __ATOMIC_RELAXED, __HIP_MEMORY_SCOPE_AGENT);
            sw[tid * 4 + 0] = fexp2(x0 * SCALE_);
            sw[tid * 4 + 1] = fexp2(x1 * SCALE_);
            sw[tid * 4 + 2] = fexp2(x2 * SCALE_);
            sw[tid * 4 + 3] = fexp2(x3 * SCALE_);
            __syncthreads();
            float wrg[16];
#pragma unroll
            for (int i4 = 0; i4 < 4; ++i4)
                *(float4*)&wrg[i4 * 4] = ((const float4*)sw)[lane * 4 + i4];
            float del = 0.f;
#pragma unroll
            for (int rr = 0; rr < 8; ++rr) {
                const uint4* rp = (const uint4*)(Mb + ((size_t)(rbase + rr) << 10));
                uint4 A = rp[lane * 2];
                uint4 Bv = rp[lane * 2 + 1];
                float s0 = 0.f, s1 = 0.f;
                ACC8(A, 0)
                ACC8(Bv, 8)
                float s = wave_sum64(s0 + s1);
                float un = eln - EPSLN2_ * flog2(s);
                del += fabsf(un - uprev[rr]);
                uprev[rr] = un;
                if (lane == 0)
                    __hip_atomic_store(ub + rbase + rr, un, __ATOMIC_RELAXED, __HIP_MEMORY_SCOPE_AGENT);
            }
            if (lane == 0) sdel[w] = del;
            asm volatile("s_waitcnt vmcnt(0)" ::: "memory");
            __syncthreads();
            if (tid == 0) {
                __hip_atomic_fetch_add(err + t, sdel[0] + sdel[1] + sdel[2] + sdel[3],
                                       __ATOMIC_RELAXED, __HIP_MEMORY_SCOPE_AGENT);
                asm volatile("s_waitcnt vmcnt(0)" ::: "memory");
                unsigned* c = cnt + (size_t)(2 * t) * 16;
                __hip_atomic_fetch_add(c, 1u, __ATOMIC_RELAXED, __HIP_MEMORY_SCOPE_AGENT);
                while (__hip_atomic_load(c, __ATOMIC_RELAXED, __HIP_MEMORY_SCOPE_AGENT) < NBLK)
                    __builtin_amdgcn_s_sleep(1);
            }
            __syncthreads();
        }
        // ---------- v phase: symmetric with MT ----------
        {
            float x0 = __hip_atomic_load(ub + tid * 4 + 0, __ATOMIC_RELAXED, __HIP_MEMORY_SCOPE_AGENT);
            float x1 = __hip_atomic_load(ub + tid * 4 + 1, __ATOMIC_RELAXED, __HIP_MEMORY_SCOPE_AGENT);
            float x2 = __hip_atomic_load(ub + tid * 4 + 2, __ATOMIC_RELAXED, __HIP_MEMORY_SCOPE_AGENT);
            float x3 = __hip_atomic_load(ub + tid * 4 + 3, __ATOMIC_RELAXED, __HIP_MEMORY_SCOPE_AGENT);
            sw[tid * 4 + 0] = fexp2(x0 * SCALE_);
            sw[tid * 4 + 1] = fexp2(x1 * SCALE_);
            sw[tid * 4 + 2] = fexp2(x2 * SCALE_);
            sw[tid * 4 + 3] = fexp2(x3 * SCALE_);
            __syncthreads();
            float wrg[16];
#pragma unroll
            for (int i4 = 0; i4 < 4; ++i4)
                *(float4*)&wrg[i4 * 4] = ((const float4*)sw)[lane * 4 + i4];
#pragma unroll
            for (int rr = 0; rr < 8; ++rr) {
                const uint4* rp = (const uint4*)(MTb + ((size_t)(rbase + rr) << 10));
                uint4 A = rp[lane * 2];
                uint4 Bv = rp[lane * 2 + 1];
                float s0 = 0.f, s1 = 0.f;
                ACC8(A, 0)
                ACC8(Bv, 8)
                float s = wave_sum64(s0 + s1);
                float vn = eln - EPSLN2_ * flog2(s);
                if (lane == 0)
                    __hip_atomic_store(vb + rbase + rr, vn, __ATOMIC_RELAXED, __HIP_MEMORY_SCOPE_AGENT);
            }
            asm volatile("s_waitcnt vmcnt(0)" ::: "memory");
            __syncthreads();
            if (tid == 0) {
                unsigned* c = cnt + (size_t)(2 * t + 1) * 16;
                __hip_atomic_fetch_add(c, 1u, __ATOMIC_RELAXED, __HIP_MEMORY_SCOPE_AGENT);
                while (__hip_atomic_load(c, __ATOMIC_RELAXED, __HIP_MEMORY_SCOPE_AGENT) < NBLK)
                    __builtin_amdgcn_s_sleep(1);
                float e = __hip_atomic_load(err + t, __ATOMIC_RELAXED, __HIP_MEMORY_SCOPE_AGENT);
                sflag = (e < ERR_SUM_THRESH) ? 1 : 0;
            }
            __syncthreads();
            if (sflag) break;    // uniform: err[t] is final before barrier 2t completes
        }
    }
}

// ---------------- out = T@V + V, T_ij = a_i * M_ij * w_j ----------------
// 512 blocks x 256 thr; block: 16 rows x all d. V-tile in VGPRs, P broadcast via
// wave-private LDS + uniform ds_read_b128 (no readlane, no syncthreads in loop).
__global__ __launch_bounds__(256) void final_kernel(const unsigned short* __restrict__ M,
                                                    const float* __restrict__ u,
                                                    const float* __restrict__ v,
                                                    const float* __restrict__ V,
                                                    float* __restrict__ out) {
    __shared__ __align__(16) float sw[NN];
    __shared__ __align__(16) float sP[4][64][4];
    int tid = threadIdx.x;
    int w = tid >> 6, lane = tid & 63;
    int b = blockIdx.x & 7;
    int rt = blockIdx.x >> 3;            // 0..63
    int i0 = rt * 16;
    const unsigned short* Mb = M + ((size_t)b << 20);
    const float* Vb = V + ((size_t)(b << 10)) * DD;
    const float* vbp = v + (b << 10);
    const float* ubp = u + (b << 10);
    {
        float4 x = ((const float4*)vbp)[tid];
        sw[tid * 4 + 0] = fexp2(x.x * SCALE_);
        sw[tid * 4 + 1] = fexp2(x.y * SCALE_);
        sw[tid * 4 + 2] = fexp2(x.z * SCALE_);
        sw[tid * 4 + 3] = fexp2(x.w * SCALE_);
    }
    __syncthreads();
    float a4[4];
#pragma unroll
    for (int rr = 0; rr < 4; ++rr) a4[rr] = fexp2(ubp[i0 + w * 4 + rr] * SCALE_);
    const unsigned short* mr0 = Mb + ((size_t)(i0 + w * 4 + 0) << 10);
    const unsigned short* mr1 = Mb + ((size_t)(i0 + w * 4 + 1) << 10);
    const unsigned short* mr2 = Mb + ((size_t)(i0 + w * 4 + 2) << 10);
    const unsigned short* mr3 = Mb + ((size_t)(i0 + w * 4 + 3) << 10);
    float acc[4] = {0.f, 0.f, 0.f, 0.f};

    for (int j0 = 0; j0 < NN; j0 += 64) {
        float vt[64];
#pragma unroll
        for (int jj = 0; jj < 64; ++jj) vt[jj] = Vb[(size_t)(j0 + jj) * DD + lane];
        float wl = sw[j0 + lane];
        float p0 = bfu(mr0[j0 + lane]) * (wl * a4[0]);
        float p1 = bfu(mr1[j0 + lane]) * (wl * a4[1]);
        float p2 = bfu(mr2[j0 + lane]) * (wl * a4[2]);
        float p3 = bfu(mr3[j0 + lane]) * (wl * a4[3]);
        asm volatile("s_waitcnt lgkmcnt(0)" ::: "memory");  // WAR vs previous tile's reads
        *(float4*)&sP[w][lane][0] = make_float4(p0, p1, p2, p3);
        asm volatile("s_waitcnt lgkmcnt(0)" ::: "memory");  // RAW: wave-private region
#pragma unroll
        for (int jj = 0; jj < 64; ++jj) {
            float4 p = *(const float4*)&sP[w][jj][0];   // wave-uniform addr -> broadcast
            acc[0] = fmaf(p.x, vt[jj], acc[0]);
            acc[1] = fmaf(p.y, vt[jj], acc[1]);
            acc[2] = fmaf(p.z, vt[jj], acc[2]);
            acc[3] = fmaf(p.w, vt[jj], acc[3]);
        }
    }
#pragma unroll
    for (int rr = 0; rr < 4; ++rr) {
        int gi = i0 + w * 4 + rr;
        out[((size_t)(b << 10) + gi) * DD + lane] = acc[rr] + Vb[(size_t)gi * DD + lane];
    }
}

extern "C" void kernel_launch(void* const* d_in, const int* in_sizes, int n_in,
                              void* d_out, int out_size, void* d_ws, size_t ws_size,
                              hipStream_t stream) {
    const float* q = (const float*)d_in[0];
    const float* k = (const float*)d_in[1];
    const float* V = (const float*)d_in[2];
    float* out = (float*)d_out;

    char* ws = (char*)d_ws;
    const size_t MB16 = (size_t)BB * NN * NN * sizeof(unsigned short);   // 16 MB
    unsigned short* M  = (unsigned short*)ws;
    unsigned short* MT = (unsigned short*)(ws + MB16);
    float* u   = (float*)(ws + 2 * MB16);
    float* v   = u + BB * NN;
    float* err = v + BB * NN;
    unsigned* cnt = (unsigned*)(err + 128);

    // zero u, v, err, barrier counters (ws is re-poisoned before every call)
    size_t zbytes = (size_t)(2 * BB * NN + 128) * 4 + (size_t)(2 * MAX_ITER) * 64;
    hipMemsetAsync(u, 0, zbytes, stream);

    cost_kernel<<<dim3(16, 16, 8), dim3(16, 16), 0, stream>>>(q, k, M, MT);

    float eln = EPSF * logf(1.0f / NN + 1e-8f);
    void* args[7];
    args[0] = &M; args[1] = &MT; args[2] = &u; args[3] = &v;
    args[4] = &err; args[5] = &cnt; args[6] = &eln;
    hipLaunchCooperativeKernel((const void*)sink_coop, dim3(NBLK), dim3(256),
                               args, 0, stream);

    final_kernel<<<512, 256, 0, stream>>>(M, u, v, V, out);
}

// Round 6
// 261.062 us; speedup vs baseline: 7.9646x; 1.3430x over previous
//
#include <hip/hip_runtime.h>
#include <math.h>

#define BB 8
#define NN 1024
#define DD 64
#define EPSF 0.05f
#define MAX_ITER 100
// threshold on SUM of |du| over B*N (reference: mean < 1e-6)
#define ERR_SUM_THRESH 8.192e-3f
// 1/(eps*ln2) and eps*ln2
#define SCALE_ 28.853900817779268f
#define EPSLN2_ 0.034657359027997264f
#define NBLK 256
#define NPER 32   // blocks per batch barrier

static __device__ __forceinline__ float fexp2(float x) { return __builtin_amdgcn_exp2f(x); }
static __device__ __forceinline__ float flog2(float x) { return __builtin_amdgcn_logf(x); }
static __device__ __forceinline__ float bflo(unsigned u) { return __uint_as_float(u << 16); }
static __device__ __forceinline__ float bfhi(unsigned u) { return __uint_as_float(u & 0xffff0000u); }
static __device__ __forceinline__ float bfu(unsigned short s) { return __uint_as_float(((unsigned)s) << 16); }
static __device__ __forceinline__ unsigned short bf16rne(float x) {
    unsigned u = __float_as_uint(x);
    u += 0x7fffu + ((u >> 16) & 1u);
    return (unsigned short)(u >> 16);
}
__device__ __forceinline__ float wave_sum64(float x) {
#pragma unroll
    for (int off = 1; off < 64; off <<= 1) x += __shfl_xor(x, off);
    return x;
}

// ---- compact metadata layout: 78,336 B past the two 16MB matrices (R3-proven bound) ----
#define ERRIDX(t, b) ((b) * 128 + (t))   // err: 1024 floats
#define CNTIDX(p, b) ((b) * 256 + (p))   // cnt: 2048 u32
#define PUBIDX(t) (t)                    // pub: 128 u32
// padded LDS index: conflict-free for stride-4 writes and stride-16 reads
#define SWIDX(j) ((j) + ((j) >> 4))

// ---------------- fused normalize + cost + exp: M = exp2(-(1-QnKn^T)*SCALE_) bf16, + MT ----------------
__global__ __launch_bounds__(256) void cost_kernel(const float* __restrict__ q,
                                                   const float* __restrict__ k,
                                                   unsigned short* __restrict__ M,
                                                   unsigned short* __restrict__ MT) {
    __shared__ __align__(16) float Qs[64][65];
    __shared__ __align__(16) float Ks[64][65];
    __shared__ float qin[64];
    __shared__ float kin[64];
    int b = blockIdx.z;
    int i0 = blockIdx.y * 64, j0 = blockIdx.x * 64;
    const float* Qb = q + ((size_t)b * NN + i0) * DD;
    const float* Kb = k + ((size_t)b * NN + j0) * DD;
    int tx = threadIdx.x, ty = threadIdx.y;
    int tid = ty * 16 + tx;
#pragma unroll
    for (int kk = 0; kk < 4; ++kk) {
        int c = tid + 256 * kk;
        int row = c >> 4;
        int c4 = c & 15;
        float4 qv = ((const float4*)(Qb + row * DD))[c4];
        Qs[row][c4 * 4 + 0] = qv.x; Qs[row][c4 * 4 + 1] = qv.y;
        Qs[row][c4 * 4 + 2] = qv.z; Qs[row][c4 * 4 + 3] = qv.w;
        float4 kv = ((const float4*)(Kb + row * DD))[c4];
        Ks[row][c4 * 4 + 0] = kv.x; Ks[row][c4 * 4 + 1] = kv.y;
        Ks[row][c4 * 4 + 2] = kv.z; Ks[row][c4 * 4 + 3] = kv.w;
    }
    __syncthreads();
    if (tid < 64) {
        float ss = 0.f;
#pragma unroll 16
        for (int d = 0; d < 64; ++d) ss += Qs[tid][d] * Qs[tid][d];
        qin[tid] = 1.0f / fmaxf(sqrtf(ss), 1e-12f);
    } else if (tid < 128) {
        int r = tid - 64;
        float ss = 0.f;
#pragma unroll 16
        for (int d = 0; d < 64; ++d) ss += Ks[r][d] * Ks[r][d];
        kin[r] = 1.0f / fmaxf(sqrtf(ss), 1e-12f);
    }
    __syncthreads();
    float acc[4][4] = {};
#pragma unroll 16
    for (int d = 0; d < 64; ++d) {
        float qv[4], kv[4];
#pragma unroll
        for (int rr = 0; rr < 4; ++rr) qv[rr] = Qs[ty * 4 + rr][d];
#pragma unroll
        for (int cc = 0; cc < 4; ++cc) kv[cc] = Ks[tx * 4 + cc][d];
#pragma unroll
        for (int rr = 0; rr < 4; ++rr)
#pragma unroll
            for (int cc = 0; cc < 4; ++cc) acc[rr][cc] += qv[rr] * kv[cc];
    }
    unsigned short us[4][4];
#pragma unroll
    for (int rr = 0; rr < 4; ++rr)
#pragma unroll
        for (int cc = 0; cc < 4; ++cc) {
            float cv = 1.0f - acc[rr][cc] * qin[ty * 4 + rr] * kin[tx * 4 + cc];
            us[rr][cc] = bf16rne(fexp2(-cv * SCALE_));
        }
    // M: coalesced packed stores
#pragma unroll
    for (int rr = 0; rr < 4; ++rr) {
        uint2 m2;
        m2.x = (unsigned)us[rr][0] | ((unsigned)us[rr][1] << 16);
        m2.y = (unsigned)us[rr][2] | ((unsigned)us[rr][3] << 16);
        *(uint2*)(M + ((size_t)b << 20) + ((size_t)(i0 + ty * 4 + rr) << 10) + j0 + tx * 4) = m2;
    }
    // MT: transpose through LDS (reuse Qs storage), then coalesced stores
    __syncthreads();
    unsigned short* tT = (unsigned short*)&Qs[0][0];   // pitch 68 shorts
#pragma unroll
    for (int cc = 0; cc < 4; ++cc) {
        uint2 t2;
        t2.x = (unsigned)us[0][cc] | ((unsigned)us[1][cc] << 16);
        t2.y = (unsigned)us[2][cc] | ((unsigned)us[3][cc] << 16);
        *(uint2*)&tT[(tx * 4 + cc) * 68 + ty * 4] = t2;
    }
    __syncthreads();
#pragma unroll
    for (int r4 = 0; r4 < 4; ++r4) {
        int row = r4 * 16 + (tid >> 4);
        int c4 = (tid & 15) * 4;
        uint2 x = *(uint2*)&tT[row * 68 + c4];
        *(uint2*)(MT + ((size_t)b << 20) + ((size_t)(j0 + row) << 10) + i0 + c4) = x;
    }
}

// ---------------- persistent Sinkhorn, per-batch barriers (NO fused epilogue) ----------------
// 256 blocks x 256 threads. batch = blk&7 (32 blocks/batch). Block owns 32 M-rows +
// 32 MT-rows; wave owns 8 each. Cross-batch coupling ONLY through the convergence
// test, resolved locally when err_b >= THRESH (non-negativity of |du| sums).
#define ACC8(U4, base)                                              \
    s0 = fmaf(bflo(U4.x), wrg[base + 0], s0);                       \
    s1 = fmaf(bfhi(U4.x), wrg[base + 1], s1);                       \
    s0 = fmaf(bflo(U4.y), wrg[base + 2], s0);                       \
    s1 = fmaf(bfhi(U4.y), wrg[base + 3], s1);                       \
    s0 = fmaf(bflo(U4.z), wrg[base + 4], s0);                       \
    s1 = fmaf(bfhi(U4.z), wrg[base + 5], s1);                       \
    s0 = fmaf(bflo(U4.w), wrg[base + 6], s0);                       \
    s1 = fmaf(bfhi(U4.w), wrg[base + 7], s1);

__global__ __launch_bounds__(256, 1) void sink_coop(const unsigned short* __restrict__ M,
                                                    const unsigned short* __restrict__ MT,
                                                    float* __restrict__ u,
                                                    float* __restrict__ v,
                                                    float* __restrict__ err,
                                                    unsigned* __restrict__ cnt,
                                                    unsigned* __restrict__ pub,
                                                    float eln) {
    __shared__ __align__(16) float sw[NN + 64];
    __shared__ float sdel[4];
    __shared__ int sflag;
    int tid = threadIdx.x;
    int w = tid >> 6, lane = tid & 63;
    int b = blockIdx.x & 7;
    int slice = blockIdx.x >> 3;          // 0..31
    int rbase = slice * 32 + w * 8;       // wave's first local row
    const unsigned short* Mb  = M  + ((size_t)b << 20);
    const unsigned short* MTb = MT + ((size_t)b << 20);
    float* ub = u + (b << 10);
    float* vb = v + (b << 10);
    float uprev[8];
#pragma unroll
    for (int r = 0; r < 8; ++r) uprev[r] = 0.f;

    for (int t = 0; t < MAX_ITER; ++t) {
        // ---------- u phase ----------
        {
#pragma unroll
            for (int kk = 0; kk < 4; ++kk) {
                float x = __hip_atomic_load(vb + tid * 4 + kk, __ATOMIC_RELAXED, __HIP_MEMORY_SCOPE_AGENT);
                sw[SWIDX(tid * 4 + kk)] = fexp2(x * SCALE_);
            }
            __syncthreads();
            float wrg[16];
#pragma unroll
            for (int kk = 0; kk < 16; ++kk) wrg[kk] = sw[lane * 17 + kk];
            float del = 0.f;
#pragma unroll
            for (int rr = 0; rr < 8; ++rr) {
                const uint4* rp = (const uint4*)(Mb + ((size_t)(rbase + rr) << 10));
                uint4 A = rp[lane * 2];
                uint4 Bv = rp[lane * 2 + 1];
                float s0 = 0.f, s1 = 0.f;
                ACC8(A, 0)
                ACC8(Bv, 8)
                float s = wave_sum64(s0 + s1);
                float un = eln - EPSLN2_ * flog2(s);
                del += fabsf(un - uprev[rr]);
                uprev[rr] = un;
                if (lane == 0)
                    __hip_atomic_store(ub + rbase + rr, un, __ATOMIC_RELAXED, __HIP_MEMORY_SCOPE_AGENT);
            }
            if (lane == 0) sdel[w] = del;
            asm volatile("s_waitcnt vmcnt(0)" ::: "memory");
            __syncthreads();
            if (tid == 0) {
                __hip_atomic_fetch_add(err + ERRIDX(t, b), sdel[0] + sdel[1] + sdel[2] + sdel[3],
                                       __ATOMIC_RELAXED, __HIP_MEMORY_SCOPE_AGENT);
                asm volatile("s_waitcnt vmcnt(0)" ::: "memory");
                unsigned* c = cnt + CNTIDX(2 * t, b);
                __hip_atomic_fetch_add(c, 1u, __ATOMIC_RELAXED, __HIP_MEMORY_SCOPE_AGENT);
                while (__hip_atomic_load(c, __ATOMIC_RELAXED, __HIP_MEMORY_SCOPE_AGENT) < NPER)
                    __builtin_amdgcn_s_sleep(1);
                if (slice == 0) {   // err_b[t] now final: publish for cross-batch check
                    asm volatile("s_waitcnt vmcnt(0)" ::: "memory");
                    __hip_atomic_fetch_add(pub + PUBIDX(t), 1u, __ATOMIC_RELAXED, __HIP_MEMORY_SCOPE_AGENT);
                }
            }
            __syncthreads();
        }
        // ---------- v phase ----------
        {
#pragma unroll
            for (int kk = 0; kk < 4; ++kk) {
                float x = __hip_atomic_load(ub + tid * 4 + kk, __ATOMIC_RELAXED, __HIP_MEMORY_SCOPE_AGENT);
                sw[SWIDX(tid * 4 + kk)] = fexp2(x * SCALE_);
            }
            __syncthreads();
            float wrg[16];
#pragma unroll
            for (int kk = 0; kk < 16; ++kk) wrg[kk] = sw[lane * 17 + kk];
#pragma unroll
            for (int rr = 0; rr < 8; ++rr) {
                const uint4* rp = (const uint4*)(MTb + ((size_t)(rbase + rr) << 10));
                uint4 A = rp[lane * 2];
                uint4 Bv = rp[lane * 2 + 1];
                float s0 = 0.f, s1 = 0.f;
                ACC8(A, 0)
                ACC8(Bv, 8)
                float s = wave_sum64(s0 + s1);
                float vn = eln - EPSLN2_ * flog2(s);
                if (lane == 0)
                    __hip_atomic_store(vb + rbase + rr, vn, __ATOMIC_RELAXED, __HIP_MEMORY_SCOPE_AGENT);
            }
            asm volatile("s_waitcnt vmcnt(0)" ::: "memory");
            __syncthreads();
            if (tid == 0) {
                unsigned* c = cnt + CNTIDX(2 * t + 1, b);
                __hip_atomic_fetch_add(c, 1u, __ATOMIC_RELAXED, __HIP_MEMORY_SCOPE_AGENT);
                while (__hip_atomic_load(c, __ATOMIC_RELAXED, __HIP_MEMORY_SCOPE_AGENT) < NPER)
                    __builtin_amdgcn_s_sleep(1);
                float eb = __hip_atomic_load(err + ERRIDX(t, b), __ATOMIC_RELAXED, __HIP_MEMORY_SCOPE_AGENT);
                int brk = 0;
                if (eb < ERR_SUM_THRESH) {
                    // own contribution below threshold: need the true global sum
                    while (__hip_atomic_load(pub + PUBIDX(t), __ATOMIC_RELAXED, __HIP_MEMORY_SCOPE_AGENT) < 8u)
                        __builtin_amdgcn_s_sleep(1);
                    float s = 0.f;
                    for (int bb = 0; bb < 8; ++bb)
                        s += __hip_atomic_load(err + ERRIDX(t, bb), __ATOMIC_RELAXED, __HIP_MEMORY_SCOPE_AGENT);
                    brk = (s < ERR_SUM_THRESH);
                }
                sflag = brk;
            }
            __syncthreads();
            if (sflag) break;
        }
    }
}

// ---------------- out = T@V + V, T_ij = a_i * M_ij * w_j  (verbatim R3-proven) ----------------
__global__ __launch_bounds__(256) void final_kernel(const unsigned short* __restrict__ M,
                                                    const float* __restrict__ u,
                                                    const float* __restrict__ v,
                                                    const float* __restrict__ V,
                                                    float* __restrict__ out) {
    __shared__ __align__(16) float sw[NN];
    __shared__ __align__(16) float sP[4][64][4];
    int tid = threadIdx.x;
    int w = tid >> 6, lane = tid & 63;
    int b = blockIdx.x & 7;
    int rt = blockIdx.x >> 3;            // 0..63
    int i0 = rt * 16;
    const unsigned short* Mb = M + ((size_t)b << 20);
    const float* Vb = V + ((size_t)(b << 10)) * DD;
    const float* vbp = v + (b << 10);
    const float* ubp = u + (b << 10);
    {
        float4 x = ((const float4*)vbp)[tid];
        sw[tid * 4 + 0] = fexp2(x.x * SCALE_);
        sw[tid * 4 + 1] = fexp2(x.y * SCALE_);
        sw[tid * 4 + 2] = fexp2(x.z * SCALE_);
        sw[tid * 4 + 3] = fexp2(x.w * SCALE_);
    }
    __syncthreads();
    float a4[4];
#pragma unroll
    for (int rr = 0; rr < 4; ++rr) a4[rr] = fexp2(ubp[i0 + w * 4 + rr] * SCALE_);
    const unsigned short* mr0 = Mb + ((size_t)(i0 + w * 4 + 0) << 10);
    const unsigned short* mr1 = Mb + ((size_t)(i0 + w * 4 + 1) << 10);
    const unsigned short* mr2 = Mb + ((size_t)(i0 + w * 4 + 2) << 10);
    const unsigned short* mr3 = Mb + ((size_t)(i0 + w * 4 + 3) << 10);
    float acc[4] = {0.f, 0.f, 0.f, 0.f};

    for (int j0 = 0; j0 < NN; j0 += 64) {
        float vt[64];
#pragma unroll
        for (int jj = 0; jj < 64; ++jj) vt[jj] = Vb[(size_t)(j0 + jj) * DD + lane];
        float wl = sw[j0 + lane];
        float p0 = bfu(mr0[j0 + lane]) * (wl * a4[0]);
        float p1 = bfu(mr1[j0 + lane]) * (wl * a4[1]);
        float p2 = bfu(mr2[j0 + lane]) * (wl * a4[2]);
        float p3 = bfu(mr3[j0 + lane]) * (wl * a4[3]);
        asm volatile("s_waitcnt lgkmcnt(0)" ::: "memory");  // WAR vs previous tile's reads
        *(float4*)&sP[w][lane][0] = make_float4(p0, p1, p2, p3);
        asm volatile("s_waitcnt lgkmcnt(0)" ::: "memory");  // RAW: wave-private region
#pragma unroll
        for (int jj = 0; jj < 64; ++jj) {
            float4 p = *(const float4*)&sP[w][jj][0];   // wave-uniform addr -> broadcast
            acc[0] = fmaf(p.x, vt[jj], acc[0]);
            acc[1] = fmaf(p.y, vt[jj], acc[1]);
            acc[2] = fmaf(p.z, vt[jj], acc[2]);
            acc[3] = fmaf(p.w, vt[jj], acc[3]);
        }
    }
#pragma unroll
    for (int rr = 0; rr < 4; ++rr) {
        int gi = i0 + w * 4 + rr;
        out[((size_t)(b << 10) + gi) * DD + lane] = acc[rr] + Vb[(size_t)gi * DD + lane];
    }
}

extern "C" void kernel_launch(void* const* d_in, const int* in_sizes, int n_in,
                              void* d_out, int out_size, void* d_ws, size_t ws_size,
                              hipStream_t stream) {
    const float* q = (const float*)d_in[0];
    const float* k = (const float*)d_in[1];
    const float* V = (const float*)d_in[2];
    float* out = (float*)d_out;

    char* ws = (char*)d_ws;
    const size_t MB16 = (size_t)BB * NN * NN * sizeof(unsigned short);   // 16 MB
    unsigned short* M  = (unsigned short*)ws;
    unsigned short* MT = (unsigned short*)(ws + MB16);
    float* u   = (float*)(ws + 2 * MB16);
    float* v   = u + BB * NN;                 // 8192 floats
    float* err = v + BB * NN;                 // 1024 floats (b*128+t)
    unsigned* cnt = (unsigned*)(err + 1024);  // 2048 u32 (b*256+p)
    unsigned* pub = cnt + 2048;               // 128 u32 (t)

    // total metadata = (16384+1024+2048+128)*4 = 78,336 B <= R3-proven 78,848 B
    size_t zbytes = (size_t)(2 * BB * NN + 1024 + 2048 + 128) * 4;
    hipMemsetAsync(u, 0, zbytes, stream);

    cost_kernel<<<dim3(16, 16, 8), dim3(16, 16), 0, stream>>>(q, k, M, MT);

    float eln = EPSF * logf(1.0f / NN + 1e-8f);
    void* args[8];
    args[0] = &M; args[1] = &MT; args[2] = &u; args[3] = &v;
    args[4] = &err; args[5] = &cnt; args[6] = &pub; args[7] = &eln;
    hipLaunchCooperativeKernel((const void*)sink_coop, dim3(NBLK), dim3(256),
                               args, 0, stream);

    final_kernel<<<512, 256, 0, stream>>>(M, u, v, V, out);
}

// Round 7
// 234.156 us; speedup vs baseline: 8.8797x; 1.1149x over previous
//
#include <hip/hip_runtime.h>
#include <math.h>

#define BB 8
#define NN 1024
#define DD 64
#define EPSF 0.05f
#define MAX_ITER 100
// threshold on SUM of |du| over B*N (reference: mean < 1e-6)
#define ERR_SUM_THRESH 8.192e-3f
// 1/(eps*ln2) and eps*ln2
#define SCALE_ 28.853900817779268f
#define EPSLN2_ 0.034657359027997264f
#define NBLK 256
#define NPER 32   // blocks per batch barrier

static __device__ __forceinline__ float fexp2(float x) { return __builtin_amdgcn_exp2f(x); }
static __device__ __forceinline__ float flog2(float x) { return __builtin_amdgcn_logf(x); }
static __device__ __forceinline__ float bflo(unsigned u) { return __uint_as_float(u << 16); }
static __device__ __forceinline__ float bfu(unsigned short s) { return __uint_as_float(((unsigned)s) << 16); }
static __device__ __forceinline__ unsigned short bf16rne(float x) {
    unsigned u = __float_as_uint(x);
    u += 0x7fffu + ((u >> 16) & 1u);
    return (unsigned short)(u >> 16);
}
__device__ __forceinline__ float wave_sum64(float x) {
#pragma unroll
    for (int off = 1; off < 64; off <<= 1) x += __shfl_xor(x, off);
    return x;
}

// ---- compact metadata layout: 78,336 B past the two 16MB matrices (R3-proven bound) ----
#define ERRIDX(t, b) ((b) * 128 + (t))   // err: 1024 floats
#define CNTIDX(p, b) ((b) * 256 + (p))   // cnt: 2048 u32
#define PUBIDX(t) (t)                    // pub: 128 u32
// pitch-20 padded LDS index: j + 4*(j>>4). float4-write clean, 16B-aligned
// b128 reads at lane*20 (conflict-even: 20L%32 spans all 8 bank-quads per 8 lanes)
#define SWIDX2(j) ((j) + 4 * ((j) >> 4))

// ---------------- fused normalize + cost + exp: M = exp2(-(1-QnKn^T)*SCALE_) bf16, + MT ----------------
__global__ __launch_bounds__(256) void cost_kernel(const float* __restrict__ q,
                                                   const float* __restrict__ k,
                                                   unsigned short* __restrict__ M,
                                                   unsigned short* __restrict__ MT) {
    __shared__ __align__(16) float Qs[64][65];
    __shared__ __align__(16) float Ks[64][65];
    __shared__ float qin[64];
    __shared__ float kin[64];
    int b = blockIdx.z;
    int i0 = blockIdx.y * 64, j0 = blockIdx.x * 64;
    const float* Qb = q + ((size_t)b * NN + i0) * DD;
    const float* Kb = k + ((size_t)b * NN + j0) * DD;
    int tx = threadIdx.x, ty = threadIdx.y;
    int tid = ty * 16 + tx;
#pragma unroll
    for (int kk = 0; kk < 4; ++kk) {
        int c = tid + 256 * kk;
        int row = c >> 4;
        int c4 = c & 15;
        float4 qv = ((const float4*)(Qb + row * DD))[c4];
        Qs[row][c4 * 4 + 0] = qv.x; Qs[row][c4 * 4 + 1] = qv.y;
        Qs[row][c4 * 4 + 2] = qv.z; Qs[row][c4 * 4 + 3] = qv.w;
        float4 kv = ((const float4*)(Kb + row * DD))[c4];
        Ks[row][c4 * 4 + 0] = kv.x; Ks[row][c4 * 4 + 1] = kv.y;
        Ks[row][c4 * 4 + 2] = kv.z; Ks[row][c4 * 4 + 3] = kv.w;
    }
    __syncthreads();
    if (tid < 64) {
        float ss = 0.f;
#pragma unroll 16
        for (int d = 0; d < 64; ++d) ss += Qs[tid][d] * Qs[tid][d];
        qin[tid] = 1.0f / fmaxf(sqrtf(ss), 1e-12f);
    } else if (tid < 128) {
        int r = tid - 64;
        float ss = 0.f;
#pragma unroll 16
        for (int d = 0; d < 64; ++d) ss += Ks[r][d] * Ks[r][d];
        kin[r] = 1.0f / fmaxf(sqrtf(ss), 1e-12f);
    }
    __syncthreads();
    float acc[4][4] = {};
#pragma unroll 16
    for (int d = 0; d < 64; ++d) {
        float qv[4], kv[4];
#pragma unroll
        for (int rr = 0; rr < 4; ++rr) qv[rr] = Qs[ty * 4 + rr][d];
#pragma unroll
        for (int cc = 0; cc < 4; ++cc) kv[cc] = Ks[tx * 4 + cc][d];
#pragma unroll
        for (int rr = 0; rr < 4; ++rr)
#pragma unroll
            for (int cc = 0; cc < 4; ++cc) acc[rr][cc] += qv[rr] * kv[cc];
    }
    unsigned short us[4][4];
#pragma unroll
    for (int rr = 0; rr < 4; ++rr)
#pragma unroll
        for (int cc = 0; cc < 4; ++cc) {
            float cv = 1.0f - acc[rr][cc] * qin[ty * 4 + rr] * kin[tx * 4 + cc];
            us[rr][cc] = bf16rne(fexp2(-cv * SCALE_));
        }
    // M: coalesced packed stores
#pragma unroll
    for (int rr = 0; rr < 4; ++rr) {
        uint2 m2;
        m2.x = (unsigned)us[rr][0] | ((unsigned)us[rr][1] << 16);
        m2.y = (unsigned)us[rr][2] | ((unsigned)us[rr][3] << 16);
        *(uint2*)(M + ((size_t)b << 20) + ((size_t)(i0 + ty * 4 + rr) << 10) + j0 + tx * 4) = m2;
    }
    // MT: transpose through LDS (reuse Qs storage), then coalesced stores
    __syncthreads();
    unsigned short* tT = (unsigned short*)&Qs[0][0];   // pitch 68 shorts
#pragma unroll
    for (int cc = 0; cc < 4; ++cc) {
        uint2 t2;
        t2.x = (unsigned)us[0][cc] | ((unsigned)us[1][cc] << 16);
        t2.y = (unsigned)us[2][cc] | ((unsigned)us[3][cc] << 16);
        *(uint2*)&tT[(tx * 4 + cc) * 68 + ty * 4] = t2;
    }
    __syncthreads();
#pragma unroll
    for (int r4 = 0; r4 < 4; ++r4) {
        int row = r4 * 16 + (tid >> 4);
        int c4 = (tid & 15) * 4;
        uint2 x = *(uint2*)&tT[row * 68 + c4];
        *(uint2*)(MT + ((size_t)b << 20) + ((size_t)(j0 + row) << 10) + i0 + c4) = x;
    }
}

// ---------------- persistent Sinkhorn, per-batch barriers, register-resident M/MT ----------------
// 256 blocks x 256 threads. batch = blk&7 (32 blocks/batch). Block owns 32 M-rows +
// 32 MT-rows; wave owns 8 each, held in VGPRs across all 100 iterations (zero global
// matrix traffic in the loop). Hi bf16 of each packed pair is read WITHOUT masking the
// low half (<= +0.78% mantissa noise, same order as bf16 rounding; Sinkhorn fixed-point
// self-corrects — verified margin 6x at absmax 0.0156 vs 0.0925).
#define ACC8(U4, base)                                              \
    s0 = fmaf(bflo(U4.x), wrg[base + 0], s0);                       \
    s1 = fmaf(__uint_as_float(U4.x), wrg[base + 1], s1);            \
    s0 = fmaf(bflo(U4.y), wrg[base + 2], s0);                       \
    s1 = fmaf(__uint_as_float(U4.y), wrg[base + 3], s1);            \
    s0 = fmaf(bflo(U4.z), wrg[base + 4], s0);                       \
    s1 = fmaf(__uint_as_float(U4.z), wrg[base + 5], s1);            \
    s0 = fmaf(bflo(U4.w), wrg[base + 6], s0);                       \
    s1 = fmaf(__uint_as_float(U4.w), wrg[base + 7], s1);

__global__ __launch_bounds__(256, 1) void sink_coop(const unsigned short* __restrict__ M,
                                                    const unsigned short* __restrict__ MT,
                                                    float* __restrict__ u,
                                                    float* __restrict__ v,
                                                    float* __restrict__ err,
                                                    unsigned* __restrict__ cnt,
                                                    unsigned* __restrict__ pub,
                                                    float eln) {
    __shared__ __align__(16) float sw[1280];   // pitch-20 padded (SWIDX2)
    __shared__ float sdel[4];
    __shared__ int sflag;
    int tid = threadIdx.x;
    int w = tid >> 6, lane = tid & 63;
    int b = blockIdx.x & 7;
    int slice = blockIdx.x >> 3;          // 0..31
    int rbase = slice * 32 + w * 8;       // wave's first local row
    const unsigned short* Mb  = M  + ((size_t)b << 20);
    const unsigned short* MTb = MT + ((size_t)b << 20);
    float* ub = u + (b << 10);
    float* vb = v + (b << 10);

    // ---- preload this wave's 8 M-rows + 8 MT-rows into registers (lane owns j=lane*16..+15) ----
    uint4 mA[8], mB[8], nA[8], nB[8];
#pragma unroll
    for (int r = 0; r < 8; ++r) {
        const uint4* rp = (const uint4*)(Mb + ((size_t)(rbase + r) << 10));
        mA[r] = rp[lane * 2];
        mB[r] = rp[lane * 2 + 1];
        const uint4* tp = (const uint4*)(MTb + ((size_t)(rbase + r) << 10));
        nA[r] = tp[lane * 2];
        nB[r] = tp[lane * 2 + 1];
    }

    float uprev[8];
#pragma unroll
    for (int r = 0; r < 8; ++r) uprev[r] = 0.f;

    for (int t = 0; t < MAX_ITER; ++t) {
        // ---------- u phase ----------
        {
            float4 ex;
            ex.x = fexp2(__hip_atomic_load(vb + tid * 4 + 0, __ATOMIC_RELAXED, __HIP_MEMORY_SCOPE_AGENT) * SCALE_);
            ex.y = fexp2(__hip_atomic_load(vb + tid * 4 + 1, __ATOMIC_RELAXED, __HIP_MEMORY_SCOPE_AGENT) * SCALE_);
            ex.z = fexp2(__hip_atomic_load(vb + tid * 4 + 2, __ATOMIC_RELAXED, __HIP_MEMORY_SCOPE_AGENT) * SCALE_);
            ex.w = fexp2(__hip_atomic_load(vb + tid * 4 + 3, __ATOMIC_RELAXED, __HIP_MEMORY_SCOPE_AGENT) * SCALE_);
            *(float4*)&sw[tid * 4 + 4 * (tid >> 2)] = ex;
            __syncthreads();
            float wrg[16];
            *(float4*)&wrg[0]  = *(const float4*)&sw[lane * 20 + 0];
            *(float4*)&wrg[4]  = *(const float4*)&sw[lane * 20 + 4];
            *(float4*)&wrg[8]  = *(const float4*)&sw[lane * 20 + 8];
            *(float4*)&wrg[12] = *(const float4*)&sw[lane * 20 + 12];
            float del = 0.f;
#pragma unroll
            for (int rr = 0; rr < 8; ++rr) {
                float s0 = 0.f, s1 = 0.f;
                ACC8(mA[rr], 0)
                ACC8(mB[rr], 8)
                float s = wave_sum64(s0 + s1);
                float un = eln - EPSLN2_ * flog2(s);
                del += fabsf(un - uprev[rr]);
                uprev[rr] = un;
                if (lane == 0)
                    __hip_atomic_store(ub + rbase + rr, un, __ATOMIC_RELAXED, __HIP_MEMORY_SCOPE_AGENT);
            }
            if (lane == 0) sdel[w] = del;
            asm volatile("s_waitcnt vmcnt(0)" ::: "memory");
            __syncthreads();
            if (tid == 0) {
                __hip_atomic_fetch_add(err + ERRIDX(t, b), sdel[0] + sdel[1] + sdel[2] + sdel[3],
                                       __ATOMIC_RELAXED, __HIP_MEMORY_SCOPE_AGENT);
                asm volatile("s_waitcnt vmcnt(0)" ::: "memory");
                unsigned* c = cnt + CNTIDX(2 * t, b);
                __hip_atomic_fetch_add(c, 1u, __ATOMIC_RELAXED, __HIP_MEMORY_SCOPE_AGENT);
                while (__hip_atomic_load(c, __ATOMIC_RELAXED, __HIP_MEMORY_SCOPE_AGENT) < NPER)
                    __builtin_amdgcn_s_sleep(1);
                if (slice == 0) {   // err_b[t] now final: publish for cross-batch check
                    asm volatile("s_waitcnt vmcnt(0)" ::: "memory");
                    __hip_atomic_fetch_add(pub + PUBIDX(t), 1u, __ATOMIC_RELAXED, __HIP_MEMORY_SCOPE_AGENT);
                }
            }
            __syncthreads();
        }
        // ---------- v phase ----------
        {
            float4 ex;
            ex.x = fexp2(__hip_atomic_load(ub + tid * 4 + 0, __ATOMIC_RELAXED, __HIP_MEMORY_SCOPE_AGENT) * SCALE_);
            ex.y = fexp2(__hip_atomic_load(ub + tid * 4 + 1, __ATOMIC_RELAXED, __HIP_MEMORY_SCOPE_AGENT) * SCALE_);
            ex.z = fexp2(__hip_atomic_load(ub + tid * 4 + 2, __ATOMIC_RELAXED, __HIP_MEMORY_SCOPE_AGENT) * SCALE_);
            ex.w = fexp2(__hip_atomic_load(ub + tid * 4 + 3, __ATOMIC_RELAXED, __HIP_MEMORY_SCOPE_AGENT) * SCALE_);
            *(float4*)&sw[tid * 4 + 4 * (tid >> 2)] = ex;
            __syncthreads();
            float wrg[16];
            *(float4*)&wrg[0]  = *(const float4*)&sw[lane * 20 + 0];
            *(float4*)&wrg[4]  = *(const float4*)&sw[lane * 20 + 4];
            *(float4*)&wrg[8]  = *(const float4*)&sw[lane * 20 + 8];
            *(float4*)&wrg[12] = *(const float4*)&sw[lane * 20 + 12];
#pragma unroll
            for (int rr = 0; rr < 8; ++rr) {
                float s0 = 0.f, s1 = 0.f;
                ACC8(nA[rr], 0)
                ACC8(nB[rr], 8)
                float s = wave_sum64(s0 + s1);
                float vn = eln - EPSLN2_ * flog2(s);
                if (lane == 0)
                    __hip_atomic_store(vb + rbase + rr, vn, __ATOMIC_RELAXED, __HIP_MEMORY_SCOPE_AGENT);
            }
            asm volatile("s_waitcnt vmcnt(0)" ::: "memory");
            __syncthreads();
            if (tid == 0) {
                unsigned* c = cnt + CNTIDX(2 * t + 1, b);
                __hip_atomic_fetch_add(c, 1u, __ATOMIC_RELAXED, __HIP_MEMORY_SCOPE_AGENT);
                while (__hip_atomic_load(c, __ATOMIC_RELAXED, __HIP_MEMORY_SCOPE_AGENT) < NPER)
                    __builtin_amdgcn_s_sleep(1);
                float eb = __hip_atomic_load(err + ERRIDX(t, b), __ATOMIC_RELAXED, __HIP_MEMORY_SCOPE_AGENT);
                int brk = 0;
                if (eb < ERR_SUM_THRESH) {
                    // own contribution below threshold: need the true global sum
                    while (__hip_atomic_load(pub + PUBIDX(t), __ATOMIC_RELAXED, __HIP_MEMORY_SCOPE_AGENT) < 8u)
                        __builtin_amdgcn_s_sleep(1);
                    float s = 0.f;
                    for (int bb = 0; bb < 8; ++bb)
                        s += __hip_atomic_load(err + ERRIDX(t, bb), __ATOMIC_RELAXED, __HIP_MEMORY_SCOPE_AGENT);
                    brk = (s < ERR_SUM_THRESH);
                }
                sflag = brk;
            }
            __syncthreads();
            if (sflag) break;
        }
    }
}

// ---------------- out = T@V + V, T_ij = a_i * M_ij * w_j  (verbatim R3-proven) ----------------
__global__ __launch_bounds__(256) void final_kernel(const unsigned short* __restrict__ M,
                                                    const float* __restrict__ u,
                                                    const float* __restrict__ v,
                                                    const float* __restrict__ V,
                                                    float* __restrict__ out) {
    __shared__ __align__(16) float sw[NN];
    __shared__ __align__(16) float sP[4][64][4];
    int tid = threadIdx.x;
    int w = tid >> 6, lane = tid & 63;
    int b = blockIdx.x & 7;
    int rt = blockIdx.x >> 3;            // 0..63
    int i0 = rt * 16;
    const unsigned short* Mb = M + ((size_t)b << 20);
    const float* Vb = V + ((size_t)(b << 10)) * DD;
    const float* vbp = v + (b << 10);
    const float* ubp = u + (b << 10);
    {
        float4 x = ((const float4*)vbp)[tid];
        sw[tid * 4 + 0] = fexp2(x.x * SCALE_);
        sw[tid * 4 + 1] = fexp2(x.y * SCALE_);
        sw[tid * 4 + 2] = fexp2(x.z * SCALE_);
        sw[tid * 4 + 3] = fexp2(x.w * SCALE_);
    }
    __syncthreads();
    float a4[4];
#pragma unroll
    for (int rr = 0; rr < 4; ++rr) a4[rr] = fexp2(ubp[i0 + w * 4 + rr] * SCALE_);
    const unsigned short* mr0 = Mb + ((size_t)(i0 + w * 4 + 0) << 10);
    const unsigned short* mr1 = Mb + ((size_t)(i0 + w * 4 + 1) << 10);
    const unsigned short* mr2 = Mb + ((size_t)(i0 + w * 4 + 2) << 10);
    const unsigned short* mr3 = Mb + ((size_t)(i0 + w * 4 + 3) << 10);
    float acc[4] = {0.f, 0.f, 0.f, 0.f};

    for (int j0 = 0; j0 < NN; j0 += 64) {
        float vt[64];
#pragma unroll
        for (int jj = 0; jj < 64; ++jj) vt[jj] = Vb[(size_t)(j0 + jj) * DD + lane];
        float wl = sw[j0 + lane];
        float p0 = bfu(mr0[j0 + lane]) * (wl * a4[0]);
        float p1 = bfu(mr1[j0 + lane]) * (wl * a4[1]);
        float p2 = bfu(mr2[j0 + lane]) * (wl * a4[2]);
        float p3 = bfu(mr3[j0 + lane]) * (wl * a4[3]);
        asm volatile("s_waitcnt lgkmcnt(0)" ::: "memory");  // WAR vs previous tile's reads
        *(float4*)&sP[w][lane][0] = make_float4(p0, p1, p2, p3);
        asm volatile("s_waitcnt lgkmcnt(0)" ::: "memory");  // RAW: wave-private region
#pragma unroll
        for (int jj = 0; jj < 64; ++jj) {
            float4 p = *(const float4*)&sP[w][jj][0];   // wave-uniform addr -> broadcast
            acc[0] = fmaf(p.x, vt[jj], acc[0]);
            acc[1] = fmaf(p.y, vt[jj], acc[1]);
            acc[2] = fmaf(p.z, vt[jj], acc[2]);
            acc[3] = fmaf(p.w, vt[jj], acc[3]);
        }
    }
#pragma unroll
    for (int rr = 0; rr < 4; ++rr) {
        int gi = i0 + w * 4 + rr;
        out[((size_t)(b << 10) + gi) * DD + lane] = acc[rr] + Vb[(size_t)gi * DD + lane];
    }
}

extern "C" void kernel_launch(void* const* d_in, const int* in_sizes, int n_in,
                              void* d_out, int out_size, void* d_ws, size_t ws_size,
                              hipStream_t stream) {
    const float* q = (const float*)d_in[0];
    const float* k = (const float*)d_in[1];
    const float* V = (const float*)d_in[2];
    float* out = (float*)d_out;

    char* ws = (char*)d_ws;
    const size_t MB16 = (size_t)BB * NN * NN * sizeof(unsigned short);   // 16 MB
    unsigned short* M  = (unsigned short*)ws;
    unsigned short* MT = (unsigned short*)(ws + MB16);
    float* u   = (float*)(ws + 2 * MB16);
    float* v   = u + BB * NN;                 // 8192 floats
    float* err = v + BB * NN;                 // 1024 floats (b*128+t)
    unsigned* cnt = (unsigned*)(err + 1024);  // 2048 u32 (b*256+p)
    unsigned* pub = cnt + 2048;               // 128 u32 (t)

    // total metadata = (16384+1024+2048+128)*4 = 78,336 B <= R3-proven 78,848 B
    size_t zbytes = (size_t)(2 * BB * NN + 1024 + 2048 + 128) * 4;
    hipMemsetAsync(u, 0, zbytes, stream);

    cost_kernel<<<dim3(16, 16, 8), dim3(16, 16), 0, stream>>>(q, k, M, MT);

    float eln = EPSF * logf(1.0f / NN + 1e-8f);
    void* args[8];
    args[0] = &M; args[1] = &MT; args[2] = &u; args[3] = &v;
    args[4] = &err; args[5] = &cnt; args[6] = &pub; args[7] = &eln;
    hipLaunchCooperativeKernel((const void*)sink_coop, dim3(NBLK), dim3(256),
                               args, 0, stream);

    final_kernel<<<512, 256, 0, stream>>>(M, u, v, V, out);
}

// Round 8
// 216.788 us; speedup vs baseline: 9.5912x; 1.0801x over previous
//
#include <hip/hip_runtime.h>
#include <math.h>

#define BB 8
#define NN 1024
#define DD 64
#define EPSF 0.05f
#define MAX_ITER 100
// threshold on SUM of |du| over B*N (reference: mean < 1e-6)
#define ERR_SUM_THRESH 8.192e-3f
// 1/(eps*ln2) and eps*ln2
#define SCALE_ 28.853900817779268f
#define EPSLN2_ 0.034657359027997264f
#define NBLK 256
#define NPER 32   // blocks per batch barrier

typedef __attribute__((ext_vector_type(8))) short short8;
typedef __attribute__((ext_vector_type(4))) float f32x4;

static __device__ __forceinline__ float fexp2(float x) { return __builtin_amdgcn_exp2f(x); }
static __device__ __forceinline__ float flog2(float x) { return __builtin_amdgcn_logf(x); }
static __device__ __forceinline__ float bflo(unsigned u) { return __uint_as_float(u << 16); }
static __device__ __forceinline__ unsigned short bf16rne(float x) {
    unsigned u = __float_as_uint(x);
    u += 0x7fffu + ((u >> 16) & 1u);
    return (unsigned short)(u >> 16);
}
__device__ __forceinline__ float wave_sum64(float x) {
#pragma unroll
    for (int off = 1; off < 64; off <<= 1) x += __shfl_xor(x, off);
    return x;
}

// ---- compact metadata layout: 78,336 B past the two 16MB matrices (R3-proven bound) ----
#define ERRIDX(t, b) ((b) * 128 + (t))   // err: 1024 floats
#define CNTIDX(p, b) ((b) * 256 + (p))   // cnt: 2048 u32
#define PUBIDX(t) (t)                    // pub: 128 u32

// ---------------- fused normalize + cost + exp: M = exp2(-(1-QnKn^T)*SCALE_) bf16, + MT ----------------
__global__ __launch_bounds__(256) void cost_kernel(const float* __restrict__ q,
                                                   const float* __restrict__ k,
                                                   unsigned short* __restrict__ M,
                                                   unsigned short* __restrict__ MT) {
    __shared__ __align__(16) float Qs[64][65];
    __shared__ __align__(16) float Ks[64][65];
    __shared__ float qin[64];
    __shared__ float kin[64];
    int b = blockIdx.z;
    int i0 = blockIdx.y * 64, j0 = blockIdx.x * 64;
    const float* Qb = q + ((size_t)b * NN + i0) * DD;
    const float* Kb = k + ((size_t)b * NN + j0) * DD;
    int tx = threadIdx.x, ty = threadIdx.y;
    int tid = ty * 16 + tx;
#pragma unroll
    for (int kk = 0; kk < 4; ++kk) {
        int c = tid + 256 * kk;
        int row = c >> 4;
        int c4 = c & 15;
        float4 qv = ((const float4*)(Qb + row * DD))[c4];
        Qs[row][c4 * 4 + 0] = qv.x; Qs[row][c4 * 4 + 1] = qv.y;
        Qs[row][c4 * 4 + 2] = qv.z; Qs[row][c4 * 4 + 3] = qv.w;
        float4 kv = ((const float4*)(Kb + row * DD))[c4];
        Ks[row][c4 * 4 + 0] = kv.x; Ks[row][c4 * 4 + 1] = kv.y;
        Ks[row][c4 * 4 + 2] = kv.z; Ks[row][c4 * 4 + 3] = kv.w;
    }
    __syncthreads();
    if (tid < 64) {
        float ss = 0.f;
#pragma unroll 16
        for (int d = 0; d < 64; ++d) ss += Qs[tid][d] * Qs[tid][d];
        qin[tid] = 1.0f / fmaxf(sqrtf(ss), 1e-12f);
    } else if (tid < 128) {
        int r = tid - 64;
        float ss = 0.f;
#pragma unroll 16
        for (int d = 0; d < 64; ++d) ss += Ks[r][d] * Ks[r][d];
        kin[r] = 1.0f / fmaxf(sqrtf(ss), 1e-12f);
    }
    __syncthreads();
    float acc[4][4] = {};
#pragma unroll 16
    for (int d = 0; d < 64; ++d) {
        float qv[4], kv[4];
#pragma unroll
        for (int rr = 0; rr < 4; ++rr) qv[rr] = Qs[ty * 4 + rr][d];
#pragma unroll
        for (int cc = 0; cc < 4; ++cc) kv[cc] = Ks[tx * 4 + cc][d];
#pragma unroll
        for (int rr = 0; rr < 4; ++rr)
#pragma unroll
            for (int cc = 0; cc < 4; ++cc) acc[rr][cc] += qv[rr] * kv[cc];
    }
    unsigned short us[4][4];
#pragma unroll
    for (int rr = 0; rr < 4; ++rr)
#pragma unroll
        for (int cc = 0; cc < 4; ++cc) {
            float cv = 1.0f - acc[rr][cc] * qin[ty * 4 + rr] * kin[tx * 4 + cc];
            us[rr][cc] = bf16rne(fexp2(-cv * SCALE_));
        }
    // M: coalesced packed stores
#pragma unroll
    for (int rr = 0; rr < 4; ++rr) {
        uint2 m2;
        m2.x = (unsigned)us[rr][0] | ((unsigned)us[rr][1] << 16);
        m2.y = (unsigned)us[rr][2] | ((unsigned)us[rr][3] << 16);
        *(uint2*)(M + ((size_t)b << 20) + ((size_t)(i0 + ty * 4 + rr) << 10) + j0 + tx * 4) = m2;
    }
    // MT: transpose through LDS (reuse Qs storage), then coalesced stores
    __syncthreads();
    unsigned short* tT = (unsigned short*)&Qs[0][0];   // pitch 68 shorts
#pragma unroll
    for (int cc = 0; cc < 4; ++cc) {
        uint2 t2;
        t2.x = (unsigned)us[0][cc] | ((unsigned)us[1][cc] << 16);
        t2.y = (unsigned)us[2][cc] | ((unsigned)us[3][cc] << 16);
        *(uint2*)&tT[(tx * 4 + cc) * 68 + ty * 4] = t2;
    }
    __syncthreads();
#pragma unroll
    for (int r4 = 0; r4 < 4; ++r4) {
        int row = r4 * 16 + (tid >> 4);
        int c4 = (tid & 15) * 4;
        uint2 x = *(uint2*)&tT[row * 68 + c4];
        *(uint2*)(MT + ((size_t)b << 20) + ((size_t)(j0 + row) << 10) + i0 + c4) = x;
    }
}

// ---------------- persistent Sinkhorn (verbatim R7-proven) ----------------
#define ACC8(U4, base)                                              \
    s0 = fmaf(bflo(U4.x), wrg[base + 0], s0);                       \
    s1 = fmaf(__uint_as_float(U4.x), wrg[base + 1], s1);            \
    s0 = fmaf(bflo(U4.y), wrg[base + 2], s0);                       \
    s1 = fmaf(__uint_as_float(U4.y), wrg[base + 3], s1);            \
    s0 = fmaf(bflo(U4.z), wrg[base + 4], s0);                       \
    s1 = fmaf(__uint_as_float(U4.z), wrg[base + 5], s1);            \
    s0 = fmaf(bflo(U4.w), wrg[base + 6], s0);                       \
    s1 = fmaf(__uint_as_float(U4.w), wrg[base + 7], s1);

__global__ __launch_bounds__(256, 1) void sink_coop(const unsigned short* __restrict__ M,
                                                    const unsigned short* __restrict__ MT,
                                                    float* __restrict__ u,
                                                    float* __restrict__ v,
                                                    float* __restrict__ err,
                                                    unsigned* __restrict__ cnt,
                                                    unsigned* __restrict__ pub,
                                                    float eln) {
    __shared__ __align__(16) float sw[1280];   // pitch-20 padded
    __shared__ float sdel[4];
    __shared__ int sflag;
    int tid = threadIdx.x;
    int w = tid >> 6, lane = tid & 63;
    int b = blockIdx.x & 7;
    int slice = blockIdx.x >> 3;          // 0..31
    int rbase = slice * 32 + w * 8;       // wave's first local row
    const unsigned short* Mb  = M  + ((size_t)b << 20);
    const unsigned short* MTb = MT + ((size_t)b << 20);
    float* ub = u + (b << 10);
    float* vb = v + (b << 10);

    // ---- preload this wave's 8 M-rows + 8 MT-rows into registers ----
    uint4 mA[8], mB[8], nA[8], nB[8];
#pragma unroll
    for (int r = 0; r < 8; ++r) {
        const uint4* rp = (const uint4*)(Mb + ((size_t)(rbase + r) << 10));
        mA[r] = rp[lane * 2];
        mB[r] = rp[lane * 2 + 1];
        const uint4* tp = (const uint4*)(MTb + ((size_t)(rbase + r) << 10));
        nA[r] = tp[lane * 2];
        nB[r] = tp[lane * 2 + 1];
    }

    float uprev[8];
#pragma unroll
    for (int r = 0; r < 8; ++r) uprev[r] = 0.f;

    for (int t = 0; t < MAX_ITER; ++t) {
        // ---------- u phase ----------
        {
            float4 ex;
            ex.x = fexp2(__hip_atomic_load(vb + tid * 4 + 0, __ATOMIC_RELAXED, __HIP_MEMORY_SCOPE_AGENT) * SCALE_);
            ex.y = fexp2(__hip_atomic_load(vb + tid * 4 + 1, __ATOMIC_RELAXED, __HIP_MEMORY_SCOPE_AGENT) * SCALE_);
            ex.z = fexp2(__hip_atomic_load(vb + tid * 4 + 2, __ATOMIC_RELAXED, __HIP_MEMORY_SCOPE_AGENT) * SCALE_);
            ex.w = fexp2(__hip_atomic_load(vb + tid * 4 + 3, __ATOMIC_RELAXED, __HIP_MEMORY_SCOPE_AGENT) * SCALE_);
            *(float4*)&sw[tid * 4 + 4 * (tid >> 2)] = ex;
            __syncthreads();
            float wrg[16];
            *(float4*)&wrg[0]  = *(const float4*)&sw[lane * 20 + 0];
            *(float4*)&wrg[4]  = *(const float4*)&sw[lane * 20 + 4];
            *(float4*)&wrg[8]  = *(const float4*)&sw[lane * 20 + 8];
            *(float4*)&wrg[12] = *(const float4*)&sw[lane * 20 + 12];
            float del = 0.f;
#pragma unroll
            for (int rr = 0; rr < 8; ++rr) {
                float s0 = 0.f, s1 = 0.f;
                ACC8(mA[rr], 0)
                ACC8(mB[rr], 8)
                float s = wave_sum64(s0 + s1);
                float un = eln - EPSLN2_ * flog2(s);
                del += fabsf(un - uprev[rr]);
                uprev[rr] = un;
                if (lane == 0)
                    __hip_atomic_store(ub + rbase + rr, un, __ATOMIC_RELAXED, __HIP_MEMORY_SCOPE_AGENT);
            }
            if (lane == 0) sdel[w] = del;
            asm volatile("s_waitcnt vmcnt(0)" ::: "memory");
            __syncthreads();
            if (tid == 0) {
                __hip_atomic_fetch_add(err + ERRIDX(t, b), sdel[0] + sdel[1] + sdel[2] + sdel[3],
                                       __ATOMIC_RELAXED, __HIP_MEMORY_SCOPE_AGENT);
                asm volatile("s_waitcnt vmcnt(0)" ::: "memory");
                unsigned* c = cnt + CNTIDX(2 * t, b);
                __hip_atomic_fetch_add(c, 1u, __ATOMIC_RELAXED, __HIP_MEMORY_SCOPE_AGENT);
                while (__hip_atomic_load(c, __ATOMIC_RELAXED, __HIP_MEMORY_SCOPE_AGENT) < NPER)
                    __builtin_amdgcn_s_sleep(1);
                if (slice == 0) {
                    asm volatile("s_waitcnt vmcnt(0)" ::: "memory");
                    __hip_atomic_fetch_add(pub + PUBIDX(t), 1u, __ATOMIC_RELAXED, __HIP_MEMORY_SCOPE_AGENT);
                }
            }
            __syncthreads();
        }
        // ---------- v phase ----------
        {
            float4 ex;
            ex.x = fexp2(__hip_atomic_load(ub + tid * 4 + 0, __ATOMIC_RELAXED, __HIP_MEMORY_SCOPE_AGENT) * SCALE_);
            ex.y = fexp2(__hip_atomic_load(ub + tid * 4 + 1, __ATOMIC_RELAXED, __HIP_MEMORY_SCOPE_AGENT) * SCALE_);
            ex.z = fexp2(__hip_atomic_load(ub + tid * 4 + 2, __ATOMIC_RELAXED, __HIP_MEMORY_SCOPE_AGENT) * SCALE_);
            ex.w = fexp2(__hip_atomic_load(ub + tid * 4 + 3, __ATOMIC_RELAXED, __HIP_MEMORY_SCOPE_AGENT) * SCALE_);
            *(float4*)&sw[tid * 4 + 4 * (tid >> 2)] = ex;
            __syncthreads();
            float wrg[16];
            *(float4*)&wrg[0]  = *(const float4*)&sw[lane * 20 + 0];
            *(float4*)&wrg[4]  = *(const float4*)&sw[lane * 20 + 4];
            *(float4*)&wrg[8]  = *(const float4*)&sw[lane * 20 + 8];
            *(float4*)&wrg[12] = *(const float4*)&sw[lane * 20 + 12];
#pragma unroll
            for (int rr = 0; rr < 8; ++rr) {
                float s0 = 0.f, s1 = 0.f;
                ACC8(nA[rr], 0)
                ACC8(nB[rr], 8)
                float s = wave_sum64(s0 + s1);
                float vn = eln - EPSLN2_ * flog2(s);
                if (lane == 0)
                    __hip_atomic_store(vb + rbase + rr, vn, __ATOMIC_RELAXED, __HIP_MEMORY_SCOPE_AGENT);
            }
            asm volatile("s_waitcnt vmcnt(0)" ::: "memory");
            __syncthreads();
            if (tid == 0) {
                unsigned* c = cnt + CNTIDX(2 * t + 1, b);
                __hip_atomic_fetch_add(c, 1u, __ATOMIC_RELAXED, __HIP_MEMORY_SCOPE_AGENT);
                while (__hip_atomic_load(c, __ATOMIC_RELAXED, __HIP_MEMORY_SCOPE_AGENT) < NPER)
                    __builtin_amdgcn_s_sleep(1);
                float eb = __hip_atomic_load(err + ERRIDX(t, b), __ATOMIC_RELAXED, __HIP_MEMORY_SCOPE_AGENT);
                int brk = 0;
                if (eb < ERR_SUM_THRESH) {
                    while (__hip_atomic_load(pub + PUBIDX(t), __ATOMIC_RELAXED, __HIP_MEMORY_SCOPE_AGENT) < 8u)
                        __builtin_amdgcn_s_sleep(1);
                    float s = 0.f;
                    for (int bb = 0; bb < 8; ++bb)
                        s += __hip_atomic_load(err + ERRIDX(t, bb), __ATOMIC_RELAXED, __HIP_MEMORY_SCOPE_AGENT);
                    brk = (s < ERR_SUM_THRESH);
                }
                sflag = brk;
            }
            __syncthreads();
            if (sflag) break;
        }
    }
}

// ---------------- WT precompute: WT[b][d][j] = bf16( exp2(v_j*S) * V[b][j][d] ) ----------------
// 128 blocks (b = blk&7, jt = blk>>3 over 16 j-tiles of 64). Overwrites the dead MT buffer.
__global__ __launch_bounds__(256) void wt_kernel(const float* __restrict__ V,
                                                 const float* __restrict__ v,
                                                 unsigned short* __restrict__ WT) {
    __shared__ __align__(16) float Vs[64][65];
    __shared__ float wj[64];
    int b = blockIdx.x & 7, jt = blockIdx.x >> 3;
    int j0 = jt * 64;
    int tid = threadIdx.x;
    const float* Vb = V + ((size_t)b << 16) + ((size_t)j0 << 6);
#pragma unroll
    for (int c = 0; c < 4; ++c) {
        int idx = tid + 256 * c;        // float4 chunk 0..1023
        int row = idx >> 4, c4 = idx & 15;
        float4 x = ((const float4*)(Vb + row * 64))[c4];
        Vs[row][c4 * 4 + 0] = x.x; Vs[row][c4 * 4 + 1] = x.y;
        Vs[row][c4 * 4 + 2] = x.z; Vs[row][c4 * 4 + 3] = x.w;
    }
    if (tid < 64) wj[tid] = fexp2(v[(b << 10) + j0 + tid] * SCALE_);
    __syncthreads();
    int d = tid >> 2, qd = tid & 3;     // thread: row d, j-quad qd (16 j each)
    unsigned pk[8];
#pragma unroll
    for (int p = 0; p < 8; ++p) {
        int j = qd * 16 + p * 2;
        unsigned lo = bf16rne(Vs[j][d] * wj[j]);
        unsigned hi = bf16rne(Vs[j + 1][d] * wj[j + 1]);
        pk[p] = lo | (hi << 16);
    }
    unsigned short* dst = WT + ((size_t)b << 16) + ((size_t)d << 10) + j0 + qd * 16;
    ((uint4*)dst)[0] = make_uint4(pk[0], pk[1], pk[2], pk[3]);
    ((uint4*)dst)[1] = make_uint4(pk[4], pk[5], pk[6], pk[7]);
}

// ---------------- MFMA epilogue: out = diag(a) * (M @ W) + V ----------------
// 256 blocks (b = blk&7, mt = blk>>3 over 32 m-tiles of 32 rows). Wave w: rows
// mt*32+(w&1)*16, cols (w>>1)*32..+31. A = M rows (bf16, row-major short8);
// "B" = WT rows (m93-verified B^T pattern: D[m][n] = sum_k A[m][k]*X[n][k]).
__global__ __launch_bounds__(256) void gemm_final(const unsigned short* __restrict__ M,
                                                  const unsigned short* __restrict__ WT,
                                                  const float* __restrict__ u,
                                                  const float* __restrict__ V,
                                                  float* __restrict__ out) {
    __shared__ float sa[32];
    int tid = threadIdx.x;
    int w = tid >> 6, lane = tid & 63;
    int b = blockIdx.x & 7, mt = blockIdx.x >> 3;
    if (tid < 32) sa[tid] = fexp2(u[(b << 10) + mt * 32 + tid] * SCALE_);
    __syncthreads();
    int m = lane & 15, q = lane >> 4;
    int rloc = (w & 1) * 16;            // wave's row offset within the 32-row tile
    int nbase = (w >> 1) * 32;          // wave's first col (2 n-tiles of 16)
    const unsigned short* Ma = M + ((size_t)b << 20) + ((size_t)(mt * 32 + rloc + m) << 10) + q * 8;
    const unsigned short* W0 = WT + ((size_t)b << 16) + ((size_t)(nbase + m) << 10) + q * 8;
    const unsigned short* W1 = W0 + (16 << 10);
    f32x4 acc0 = {0.f, 0.f, 0.f, 0.f}, acc1 = {0.f, 0.f, 0.f, 0.f};
#pragma unroll 4
    for (int k0 = 0; k0 < NN; k0 += 32) {
        short8 af = *(const short8*)(Ma + k0);
        short8 b0 = *(const short8*)(W0 + k0);
        short8 b1 = *(const short8*)(W1 + k0);
        acc0 = __builtin_amdgcn_mfma_f32_16x16x32_bf16(af, b0, acc0, 0, 0, 0);
        acc1 = __builtin_amdgcn_mfma_f32_16x16x32_bf16(af, b1, acc1, 0, 0, 0);
    }
    // C/D layout (m89-verified): col = lane&15, row = (lane>>4)*4 + reg
#pragma unroll
    for (int r = 0; r < 4; ++r) {
        int lrow = rloc + q * 4 + r;                 // local row in 32-tile
        int gm = mt * 32 + lrow;                     // global row
        float a = sa[lrow];
        size_t base = (((size_t)b << 10) + gm) * DD;
        int n0 = nbase + m;
        out[base + n0]      = fmaf(a, acc0[r], V[base + n0]);
        out[base + n0 + 16] = fmaf(a, acc1[r], V[base + n0 + 16]);
    }
}

extern "C" void kernel_launch(void* const* d_in, const int* in_sizes, int n_in,
                              void* d_out, int out_size, void* d_ws, size_t ws_size,
                              hipStream_t stream) {
    const float* q = (const float*)d_in[0];
    const float* k = (const float*)d_in[1];
    const float* V = (const float*)d_in[2];
    float* out = (float*)d_out;

    char* ws = (char*)d_ws;
    const size_t MB16 = (size_t)BB * NN * NN * sizeof(unsigned short);   // 16 MB
    unsigned short* M  = (unsigned short*)ws;
    unsigned short* MT = (unsigned short*)(ws + MB16);
    unsigned short* WT = MT;                  // MT is dead after sink; reuse (1 MB)
    float* u   = (float*)(ws + 2 * MB16);
    float* v   = u + BB * NN;                 // 8192 floats
    float* err = v + BB * NN;                 // 1024 floats (b*128+t)
    unsigned* cnt = (unsigned*)(err + 1024);  // 2048 u32 (b*256+p)
    unsigned* pub = cnt + 2048;               // 128 u32 (t)

    size_t zbytes = (size_t)(2 * BB * NN + 1024 + 2048 + 128) * 4;
    hipMemsetAsync(u, 0, zbytes, stream);

    cost_kernel<<<dim3(16, 16, 8), dim3(16, 16), 0, stream>>>(q, k, M, MT);

    float eln = EPSF * logf(1.0f / NN + 1e-8f);
    void* args[8];
    args[0] = &M; args[1] = &MT; args[2] = &u; args[3] = &v;
    args[4] = &err; args[5] = &cnt; args[6] = &pub; args[7] = &eln;
    hipLaunchCooperativeKernel((const void*)sink_coop, dim3(NBLK), dim3(256),
                               args, 0, stream);

    wt_kernel<<<128, 256, 0, stream>>>(V, v, WT);
    gemm_final<<<256, 256, 0, stream>>>(M, WT, u, V, out);
}